// Round 8
// baseline (1213.621 us; speedup 1.0000x reference)
//
#include <hip/hip_runtime.h>

#define CN0 100000
#define CN1 300000
#define CN2 200000
#define EA0 600000
#define EA1 1200000
#define EC2 600000
#define EB1 600000
#define EB2 600000
#define TOTSEG (2*CN0 + 3*CN1 + 2*CN2)           // 1,500,000
#define TOTE   (EA0 + EA1 + EC2 + 2*EB1 + 2*EB2) // 6,600,000

typedef __attribute__((ext_vector_type(8))) short short8;
typedef __attribute__((ext_vector_type(4))) float f32x4;
typedef __attribute__((ext_vector_type(4))) unsigned short u16x4;

__device__ __forceinline__ float lrelu(float v) { return v >= 0.f ? v : 0.2f * v; }
__device__ __forceinline__ unsigned short btop(float x) {
    return (unsigned short)(__float_as_uint(x) >> 16);
}
__device__ __forceinline__ unsigned short f2bf(float x) {  // RTN f32->bf16
    unsigned u = __float_as_uint(x);
    return (unsigned short)((u + 0x7FFFu + ((u >> 16) & 1u)) >> 16);
}
__device__ __forceinline__ float bf2f(unsigned short b) {
    return __uint_as_float((unsigned)b << 16);
}

struct Pats {
    const int* seg[7];
    const int* vidx[7];
    int E[7];
    int base[7];
};

// ---------------- fused CSR build (all 7 patterns) ----------------

__global__ void k_hist7(Pats P, int* __restrict__ rp1) {
    int p = blockIdx.y;
    int e = blockIdx.x * blockDim.x + threadIdx.x;
    if (e < P.E[p]) atomicAdd(&rp1[P.base[p] + P.seg[p][e]], 1);
}

__global__ void k_blkscan(int* __restrict__ d, int n, int* __restrict__ bsum) {
    __shared__ int sh[256];
    int i = blockIdx.x * 256 + threadIdx.x;
    sh[threadIdx.x] = (i < n) ? d[i] : 0;
    __syncthreads();
    for (int off = 1; off < 256; off <<= 1) {
        int t = (threadIdx.x >= (unsigned)off) ? sh[threadIdx.x - off] : 0;
        __syncthreads();
        sh[threadIdx.x] += t;
        __syncthreads();
    }
    if (i < n) d[i] = sh[threadIdx.x];
    if (threadIdx.x == 255) bsum[blockIdx.x] = sh[255];
}

__global__ void k_scanb(int* __restrict__ bsum, int nb) {
    __shared__ int sh[256];
    __shared__ int carry;
    if (threadIdx.x == 0) carry = 0;
    __syncthreads();
    for (int base = 0; base < nb; base += 256) {
        int i = base + threadIdx.x;
        sh[threadIdx.x] = (i < nb) ? bsum[i] : 0;
        __syncthreads();
        for (int off = 1; off < 256; off <<= 1) {
            int t = (threadIdx.x >= (unsigned)off) ? sh[threadIdx.x - off] : 0;
            __syncthreads();
            sh[threadIdx.x] += t;
            __syncthreads();
        }
        if (i < nb) bsum[i] = sh[threadIdx.x] + carry;
        __syncthreads();
        if (threadIdx.x == 0) carry += sh[255];
        __syncthreads();
    }
}

__global__ void k_addoff(int* __restrict__ d, const int* __restrict__ bsum, int n) {
    int i = blockIdx.x * 256 + threadIdx.x;
    if (i < n && blockIdx.x > 0) d[i] += bsum[blockIdx.x - 1];
}

// destructive scatter: rp[gs] counts up from start(gs) to end(gs)
__global__ void k_scat7(Pats P, int* __restrict__ rp, int* __restrict__ vP) {
    int p = blockIdx.y;
    int e = blockIdx.x * blockDim.x + threadIdx.x;
    if (e >= P.E[p]) return;
    int gs = P.base[p] + P.seg[p][e];
    int pos = atomicAdd(&rp[gs], 1);
    vP[pos] = P.vidx[p][e];
}

// ---------------- MFMA matmul (bf16x3 split), bf16 Y output ----------------
__global__ void mm64_mfma(const float* __restrict__ X, const float* __restrict__ W,
                          const float* __restrict__ a, unsigned short* __restrict__ Yb,
                          float* __restrict__ p, float* __restrict__ q, int nchunk) {
    int lane = threadIdx.x & 63;
    int l15 = lane & 15, lq = lane >> 4;
    int wid = blockIdx.x * (blockDim.x >> 6) + (threadIdx.x >> 6);
    int nw = gridDim.x * (blockDim.x >> 6);

    short8 bh[4][2], bl[4][2];
#pragma unroll
    for (int t = 0; t < 4; ++t)
#pragma unroll
        for (int h = 0; h < 2; ++h) {
            const float* wp = W + (size_t)(h * 32 + lq * 8) * 64 + 16 * t + l15;
#pragma unroll
            for (int j = 0; j < 8; ++j) {
                float wv = wp[(size_t)j * 64];
                unsigned short hi = btop(wv);
                float rem = wv - __uint_as_float((unsigned)hi << 16);
                bh[t][h][j] = (short)hi;
                bl[t][h][j] = (short)btop(rem);
            }
        }
    float av0[4], av1[4];
#pragma unroll
    for (int t = 0; t < 4; ++t) {
        av0[t] = a[16 * t + l15];
        av1[t] = a[64 + 16 * t + l15];
    }

    for (int c = wid; c < nchunk; c += nw) {
        int base = c * 16;
        f32x4 acc[4];
#pragma unroll
        for (int t = 0; t < 4; ++t) acc[t] = (f32x4){0.f, 0.f, 0.f, 0.f};
#pragma unroll
        for (int h = 0; h < 2; ++h) {
            const f32x4* xp = (const f32x4*)(X + (size_t)(base + l15) * 64 + h * 32 + lq * 8);
            f32x4 x0 = xp[0], x1 = xp[1];
            short8 ah, al;
#pragma unroll
            for (int j = 0; j < 4; ++j) {
                unsigned short h0 = btop(x0[j]);
                float r0 = x0[j] - __uint_as_float((unsigned)h0 << 16);
                ah[j] = (short)h0;
                al[j] = (short)btop(r0);
                unsigned short h1 = btop(x1[j]);
                float r1 = x1[j] - __uint_as_float((unsigned)h1 << 16);
                ah[4 + j] = (short)h1;
                al[4 + j] = (short)btop(r1);
            }
#pragma unroll
            for (int t = 0; t < 4; ++t) {
                acc[t] = __builtin_amdgcn_mfma_f32_16x16x32_bf16(ah, bh[t][h], acc[t], 0, 0, 0);
                acc[t] = __builtin_amdgcn_mfma_f32_16x16x32_bf16(ah, bl[t][h], acc[t], 0, 0, 0);
                acc[t] = __builtin_amdgcn_mfma_f32_16x16x32_bf16(al, bh[t][h], acc[t], 0, 0, 0);
            }
        }
#pragma unroll
        for (int t = 0; t < 4; ++t)
#pragma unroll
            for (int r = 0; r < 4; ++r)
                Yb[(size_t)(base + lq * 4 + r) * 64 + 16 * t + l15] = f2bf(acc[t][r]);
#pragma unroll
        for (int r = 0; r < 4; ++r) {
            float pr = acc[0][r] * av0[0] + acc[1][r] * av0[1] + acc[2][r] * av0[2] + acc[3][r] * av0[3];
            float qr = acc[0][r] * av1[0] + acc[1][r] * av1[1] + acc[2][r] * av1[2] + acc[3][r] * av1[3];
#pragma unroll
            for (int off = 8; off; off >>= 1) {
                pr += __shfl_xor(pr, off, 64);
                qr += __shfl_xor(qr, off, 64);
            }
            if (l15 == 0) {
                p[base + lq * 4 + r] = pr;
                q[base + lq * 4 + r] = qr;
            }
        }
    }
}

// uu[j] = W[j,:]@a[0:64]; uu[64+j] = W[j,:]@a[64:128]   (1 block x 64)
__global__ void uvec_k(const float* __restrict__ W, const float* __restrict__ a2c,
                       float* __restrict__ uu) {
    int j = threadIdx.x;
    float s0 = 0.f, s1 = 0.f;
    for (int k = 0; k < 64; ++k) {
        float w = W[j * 64 + k];
        s0 = fmaf(w, a2c[k], s0);
        s1 = fmaf(w, a2c[64 + k], s1);
    }
    uu[j] = s0;
    uu[64 + j] = s1;
}

__global__ void proj2(const float* __restrict__ X, const float* __restrict__ uu,
                      float* __restrict__ p, float* __restrict__ q, int n) {
    int lane = threadIdx.x & 63;
    int row = blockIdx.x * (blockDim.x >> 6) + (threadIdx.x >> 6);
    if (row >= n) return;
    float xv = X[(size_t)row * 64 + lane];
    float a = xv * uu[lane];
    float b = xv * uu[64 + lane];
#pragma unroll
    for (int off = 32; off; off >>= 1) {
        a += __shfl_xor(a, off, 64);
        b += __shfl_xor(b, off, 64);
    }
    if (lane == 0) { p[row] = a; q[row] = b; }
}

// ---------------- segment attention gather (16 lanes/segment) ----------------
// rp_all is POST-destructive-scatter: end(gs)=rp_all[gs], beg(gs)=rp_all[gs-1] (0 for gs==0).
__device__ __forceinline__ void seg_gather(
    const int* __restrict__ rp_all, int base, int s, const int* __restrict__ vP,
    const float* __restrict__ ps, const float* __restrict__ pv,
    const unsigned short* __restrict__ Mb, int gl, int gbase, f32x4& acc) {
    int gs = base + s;
    int end = rp_all[gs];
    int beg = gs ? rp_all[gs - 1] : 0;
    int nE = end - beg;
    if (nE <= 0) return;
    float pss = ps[s];
    if (nE <= 16) {  // fast path
        int j = beg + gl;
        int v = (j < end) ? vP[j] : 0;
        float l = (j < end) ? lrelu(pss + pv[v]) : -3.4e38f;
        float mx = l;
#pragma unroll
        for (int off = 8; off; off >>= 1) mx = fmaxf(mx, __shfl_xor(mx, off, 64));
        float ev = (j < end) ? __expf(l - mx) : 0.f;
        float ssum = ev;
#pragma unroll
        for (int off = 8; off; off >>= 1) ssum += __shfl_xor(ssum, off, 64);
        float att = ev / ssum;
        for (int t0 = 0; t0 < nE; t0 += 4) {  // batched: 4 independent loads in flight
            float w0 = __shfl(att, gbase + t0, 64), w1 = __shfl(att, gbase + t0 + 1, 64);
            float w2 = __shfl(att, gbase + t0 + 2, 64), w3 = __shfl(att, gbase + t0 + 3, 64);
            int u0 = __shfl(v, gbase + t0, 64), u1 = __shfl(v, gbase + t0 + 1, 64);
            int u2 = __shfl(v, gbase + t0 + 2, 64), u3 = __shfl(v, gbase + t0 + 3, 64);
            u16x4 m0 = *(const u16x4*)(Mb + (size_t)u0 * 64 + gl * 4);
            u16x4 m1 = *(const u16x4*)(Mb + (size_t)u1 * 64 + gl * 4);
            u16x4 m2 = *(const u16x4*)(Mb + (size_t)u2 * 64 + gl * 4);
            u16x4 m3 = *(const u16x4*)(Mb + (size_t)u3 * 64 + gl * 4);
#pragma unroll
            for (int kk = 0; kk < 4; ++kk)
                acc[kk] += w0 * bf2f(m0[kk]) + w1 * bf2f(m1[kk]) +
                           w2 * bf2f(m2[kk]) + w3 * bf2f(m3[kk]);
        }
    } else {  // general path (rare long segments)
        float mx = -3.4e38f;
        for (int j0 = beg; j0 < end; j0 += 16) {
            int j = j0 + gl;
            float l = (j < end) ? lrelu(pss + pv[vP[j]]) : -3.4e38f;
            mx = fmaxf(mx, l);
        }
#pragma unroll
        for (int off = 8; off; off >>= 1) mx = fmaxf(mx, __shfl_xor(mx, off, 64));
        float ssum = 0.f;
        for (int j0 = beg; j0 < end; j0 += 16) {
            int j = j0 + gl;
            ssum += (j < end) ? __expf(lrelu(pss + pv[vP[j]]) - mx) : 0.f;
        }
#pragma unroll
        for (int off = 8; off; off >>= 1) ssum += __shfl_xor(ssum, off, 64);
        float inv = 1.f / ssum;
        for (int j0 = beg; j0 < end; j0 += 16) {
            int j = j0 + gl;
            int v = (j < end) ? vP[j] : 0;
            float ev = (j < end) ? __expf(lrelu(pss + pv[v]) - mx) * inv : 0.f;
            int cnt = min(16, end - j0);
            for (int t0 = 0; t0 < cnt; t0 += 4) {
                float w0 = __shfl(ev, gbase + t0, 64), w1 = __shfl(ev, gbase + t0 + 1, 64);
                float w2 = __shfl(ev, gbase + t0 + 2, 64), w3 = __shfl(ev, gbase + t0 + 3, 64);
                int u0 = __shfl(v, gbase + t0, 64), u1 = __shfl(v, gbase + t0 + 1, 64);
                int u2 = __shfl(v, gbase + t0 + 2, 64), u3 = __shfl(v, gbase + t0 + 3, 64);
                u16x4 m0 = *(const u16x4*)(Mb + (size_t)u0 * 64 + gl * 4);
                u16x4 m1 = *(const u16x4*)(Mb + (size_t)u1 * 64 + gl * 4);
                u16x4 m2 = *(const u16x4*)(Mb + (size_t)u2 * 64 + gl * 4);
                u16x4 m3 = *(const u16x4*)(Mb + (size_t)u3 * 64 + gl * 4);
#pragma unroll
                for (int kk = 0; kk < 4; ++kk)
                    acc[kk] += w0 * bf2f(m0[kk]) + w1 * bf2f(m1[kk]) +
                               w2 * bf2f(m2[kk]) + w3 * bf2f(m3[kk]);
            }
        }
    }
}

__global__ void k_attn1(const int* __restrict__ rp_all, int base, const int* __restrict__ vP,
                        const float* __restrict__ ps, const float* __restrict__ pv,
                        const unsigned short* __restrict__ Mb, float* __restrict__ out,
                        int nseg) {
    int lane = threadIdx.x & 63;
    int g = lane >> 4, gl = lane & 15, gbase = g << 4;
    int s = (blockIdx.x * (blockDim.x >> 6) + (threadIdx.x >> 6)) * 4 + g;
    if (s >= nseg) return;
    f32x4 acc = (f32x4){0.f, 0.f, 0.f, 0.f};
    seg_gather(rp_all, base, s, vP, ps, pv, Mb, gl, gbase, acc);
    *(f32x4*)(out + (size_t)s * 64 + gl * 4) = acc;
}

__global__ void k_attn2(const int* __restrict__ rp_all, int baseA, int baseB,
                        const int* __restrict__ vP,
                        const float* __restrict__ psA, const float* __restrict__ pvA,
                        const unsigned short* __restrict__ MbA,
                        const float* __restrict__ psB, const float* __restrict__ pvB,
                        const unsigned short* __restrict__ MbB,
                        float* __restrict__ out, int nseg) {
    int lane = threadIdx.x & 63;
    int g = lane >> 4, gl = lane & 15, gbase = g << 4;
    int s = (blockIdx.x * (blockDim.x >> 6) + (threadIdx.x >> 6)) * 4 + g;
    if (s >= nseg) return;
    f32x4 acc = (f32x4){0.f, 0.f, 0.f, 0.f};
    seg_gather(rp_all, baseA, s, vP, psA, pvA, MbA, gl, gbase, acc);
    seg_gather(rp_all, baseB, s, vP, psB, pvB, MbB, gl, gbase, acc);
    *(f32x4*)(out + (size_t)s * 64 + gl * 4) = acc;
}

extern "C" void kernel_launch(void* const* d_in, const int* in_sizes, int n_in,
                              void* d_out, int out_size, void* d_ws, size_t ws_size,
                              hipStream_t stream) {
    (void)in_sizes; (void)n_in; (void)ws_size; (void)out_size;
    const float* x0 = (const float*)d_in[0];
    const float* x1 = (const float*)d_in[1];
    const float* x2 = (const float*)d_in[2];
    const int* adj0r = (const int*)d_in[3];
    const int* adj0c = (const int*)d_in[4];
    const int* adj1r = (const int*)d_in[5];
    const int* adj1c = (const int*)d_in[6];
    const int* co2r = (const int*)d_in[7];
    const int* co2c = (const int*)d_in[8];
    const int* i1r = (const int*)d_in[9];
    const int* i1c = (const int*)d_in[10];
    const int* i2r = (const int*)d_in[11];
    const int* i2c = (const int*)d_in[12];
    const float* W_h0_l1 = (const float*)d_in[13];
    const float* W_h0_l2 = (const float*)d_in[14];
    const float* W_h1_l2 = (const float*)d_in[15];
    const float* W_h2_l2 = (const float*)d_in[16];
    const float* Ws01_l1 = (const float*)d_in[17];
    const float* Wt01_l1 = (const float*)d_in[18];
    const float* Ws12_l1 = (const float*)d_in[19];
    const float* Wt12_l1 = (const float*)d_in[20];
    const float* Ws01_l2 = (const float*)d_in[21];
    const float* Wt01_l2 = (const float*)d_in[22];
    const float* Ws12_l2 = (const float*)d_in[23];
    const float* Wt12_l2 = (const float*)d_in[24];
    const float* a_h0_l1 = (const float*)d_in[25];
    const float* a_h0_l2 = (const float*)d_in[26];
    const float* a_h1_l2 = (const float*)d_in[27];
    const float* a_h2_l2 = (const float*)d_in[28];
    const float* a01_l1 = (const float*)d_in[29];
    const float* a12_l1 = (const float*)d_in[30];
    const float* a01_l2 = (const float*)d_in[31];
    const float* a12_l2 = (const float*)d_in[32];

    // -------- workspace layout (~175 MB) --------
    float* fb = (float*)d_ws;
    float* t0 = fb;              float* t1 = t0 + 300000;
    float* t2 = t1 + 300000;     float* t3 = t2 + 300000;
    float* t4 = t3 + 300000;     float* t5 = t4 + 300000;
    float* t6 = t5 + 300000;     float* t7 = t6 + 300000;
    float* t8 = t7 + 300000;     float* t9 = t8 + 300000;
    float* t10 = t9 + 300000;    float* t11 = t10 + 300000;
    float* uu = t11 + 300000;    // 128
    unsigned short* YA = (unsigned short*)(uu + 128);   // [CN0*64]
    unsigned short* YB = YA + (size_t)CN0 * 64;         // [CN1*64]
    unsigned short* YC = YB + (size_t)CN1 * 64;         // [CN0*64]
    unsigned short* YD = YC + (size_t)CN0 * 64;         // [CN2*64]
    unsigned short* YE = YD + (size_t)CN2 * 64;         // [CN1*64]
    int* rp_all = (int*)(YE + (size_t)CN1 * 64);        // TOTSEG+1
    int* vP_all = rp_all + (TOTSEG + 1);                // TOTE
    int* bsum   = vP_all + TOTE;                        // 6144
    int* bsum2  = bsum + 6144;                          // 64

    float* r0 = (float*)d_out;
    float* r1 = r0 + (size_t)CN0 * 64;
    float* r2 = r1 + (size_t)CN1 * 64;

    // pattern bases: A0, E1, F1, E2, F2, A1, C2
    const int bA0 = 0;
    const int bE1 = CN0;
    const int bF1 = 2 * CN0;
    const int bE2 = 2 * CN0 + CN1;
    const int bF2 = 2 * CN0 + 2 * CN1;
    const int bA1 = 2 * CN0 + 2 * CN1 + CN2;
    const int bC2 = 2 * CN0 + 3 * CN1 + CN2;
    Pats P;
    P.seg[0] = adj0r; P.vidx[0] = adj0c; P.E[0] = EA0; P.base[0] = bA0;
    P.seg[1] = i1r;   P.vidx[1] = i1c;   P.E[1] = EB1; P.base[1] = bE1;
    P.seg[2] = i1c;   P.vidx[2] = i1r;   P.E[2] = EB1; P.base[2] = bF1;
    P.seg[3] = i2r;   P.vidx[3] = i2c;   P.E[3] = EB2; P.base[3] = bE2;
    P.seg[4] = i2c;   P.vidx[4] = i2r;   P.E[4] = EB2; P.base[4] = bF2;
    P.seg[5] = adj1r; P.vidx[5] = adj1c; P.E[5] = EA1; P.base[5] = bA1;
    P.seg[6] = co2r;  P.vidx[6] = co2c;  P.E[6] = EC2; P.base[6] = bC2;
    const int Emax = EA1;

    auto MMF = [&](const float* X, const float* W, const float* a, unsigned short* Yb,
                   float* p, float* q, int n) {
        int nchunk = n / 16;
        int blocks = min(1024, (nchunk + 3) / 4);
        mm64_mfma<<<dim3(blocks), dim3(256), 0, stream>>>(X, W, a, Yb, p, q, nchunk);
    };
    auto PROJ = [&](const float* X, const float* W, const float* a2, float* p, float* q, int n) {
        uvec_k<<<dim3(1), dim3(64), 0, stream>>>(W, a2, uu);
        proj2<<<dim3((n + 3) / 4), dim3(256), 0, stream>>>(X, uu, p, q, n);
    };
    auto AGG1 = [&](int base, const float* ps, const float* pv, const unsigned short* Mb,
                    float* out, int nseg) {
        k_attn1<<<dim3((nseg + 15) / 16), dim3(256), 0, stream>>>(
            rp_all, base, vP_all, ps, pv, Mb, out, nseg);
    };
    auto AGG2 = [&](int baseA, const float* psA, const float* pvA, const unsigned short* MbA,
                    int baseB, const float* psB, const float* pvB, const unsigned short* MbB,
                    float* out, int nseg) {
        k_attn2<<<dim3((nseg + 15) / 16), dim3(256), 0, stream>>>(
            rp_all, baseA, baseB, vP_all, psA, pvA, MbA, psB, pvB, MbB, out, nseg);
    };

    // ======== fused CSR build (destructive-scan scatter) ========
    hipMemsetAsync(rp_all, 0, (size_t)(TOTSEG + 1) * 4, stream);
    {
        dim3 gh((Emax + 255) / 256, 7);
        k_hist7<<<gh, dim3(256), 0, stream>>>(P, rp_all + 1);
        int nb = (TOTSEG + 255) / 256;       // 5860
        int nb2 = (nb + 255) / 256;          // 23
        k_blkscan<<<dim3(nb), dim3(256), 0, stream>>>(rp_all + 1, TOTSEG, bsum);
        k_blkscan<<<dim3(nb2), dim3(256), 0, stream>>>(bsum, nb, bsum2);
        k_scanb<<<dim3(1), dim3(256), 0, stream>>>(bsum2, nb2);
        k_addoff<<<dim3(nb2), dim3(256), 0, stream>>>(bsum, bsum2, nb);
        k_addoff<<<dim3(nb), dim3(256), 0, stream>>>(rp_all + 1, bsum, TOTSEG);
        k_scat7<<<gh, dim3(256), 0, stream>>>(P, rp_all, vP_all);
    }

    // ======== LEVEL 1: all projections, then fused aggregations ========
    MMF(x0, W_h0_l1, a_h0_l1, YA, t0, t1, CN0);    // m0;   p,q
    MMF(x1, Ws01_l1, a01_l1, YB, t2, t3, CN1);     // sm01; ps,qs
    MMF(x0, Wt01_l1, a01_l1, YC, t4, t5, CN0);     // tm01; pt,qt
    MMF(x2, Ws12_l1, a12_l1, YD, t6, t7, CN2);     // sm12; ps,qs
    MMF(x1, Wt12_l1, a12_l1, YE, t8, t9, CN1);     // tm12; pt,qt
    AGG2(bA0, t0, t1, YA, bE1, t5, t2, YB, r0, CN0);   // x_0_to_0 + x_1_to_0
    AGG2(bF1, t3, t4, YC, bE2, t9, t6, YD, r1, CN1);   // x_0_to_1 + x_2_to_1
    AGG1(bF2, t7, t8, YE, r2, CN2);                    // x_1_to_2

    // ======== LEVEL 2: all projections (read r*), then aggregations (write r*) ====
    MMF(r0, W_h0_l2, a_h0_l2, YA, t0, t1, CN0);    // m00
    MMF(r0, Wt01_l2, a01_l2, YC, t4, t11, CN0);    // tm01; pt01->t4
    MMF(r1, W_h1_l2, a_h1_l2, YB, t2, t3, CN1);    // m11
    MMF(r1, Wt12_l2, a12_l2, YE, t8, t11, CN1);    // tm12; pt12->t8
    PROJ(r1, Ws01_l2, a01_l2, t11, t6, CN1);       // qs01->t6
    MMF(r2, W_h2_l2, a_h2_l2, YD, t7, t9, CN2);    // m22
    PROJ(r2, Ws12_l2, a12_l2, t11, t10, CN2);      // qs12->t10
    AGG1(bA0, t0, t1, YA, r0, CN0);                          // x_0_out
    AGG2(bA1, t2, t3, YB, bF1, t6, t4, YC, r1, CN1);         // x_1_to_1 + x_0_to_1
    AGG2(bC2, t7, t9, YD, bF2, t10, t8, YE, r2, CN2);        // x_2_to_2 + x_1_to_2
}

// Round 9
// 898.969 us; speedup vs baseline: 1.3500x; 1.3500x over previous
//
#include <hip/hip_runtime.h>

#define CN0 100000
#define CN1 300000
#define CN2 200000
#define EA0 600000
#define EA1 1200000
#define EC2 600000
#define EB1 600000
#define EB2 600000
#define TOTSEG (2*CN0 + 3*CN1 + 2*CN2)           // 1,500,000
#define TOTE   (EA0 + EA1 + EC2 + 2*EB1 + 2*EB2) // 6,600,000

typedef __attribute__((ext_vector_type(8))) short short8;
typedef __attribute__((ext_vector_type(4))) float f32x4;
typedef __attribute__((ext_vector_type(4))) unsigned short u16x4;

__device__ __forceinline__ float lrelu(float v) { return v >= 0.f ? v : 0.2f * v; }
__device__ __forceinline__ unsigned short btop(float x) {
    return (unsigned short)(__float_as_uint(x) >> 16);
}
__device__ __forceinline__ unsigned short f2bf(float x) {  // RTN f32->bf16
    unsigned u = __float_as_uint(x);
    return (unsigned short)((u + 0x7FFFu + ((u >> 16) & 1u)) >> 16);
}
__device__ __forceinline__ float bf2f(unsigned short b) {
    return __uint_as_float((unsigned)b << 16);
}

struct Pats {
    const int* seg[7];
    const int* vidx[7];
    int E[7];
    int base[7];
    int ebase[7];
};

// ---------------- fused CSR build (all 7 patterns) ----------------

// counts into rp1[gs] AND emits per-edge rank (coalesced write)
__global__ void k_histrank(Pats P, int* __restrict__ rp1, int* __restrict__ rank) {
    int p = blockIdx.y;
    int e = blockIdx.x * blockDim.x + threadIdx.x;
    if (e >= P.E[p]) return;
    int gs = P.base[p] + P.seg[p][e];
    rank[P.ebase[p] + e] = atomicAdd(&rp1[gs], 1);
}

__global__ void k_blkscan(int* __restrict__ d, int n, int* __restrict__ bsum) {
    __shared__ int sh[256];
    int i = blockIdx.x * 256 + threadIdx.x;
    sh[threadIdx.x] = (i < n) ? d[i] : 0;
    __syncthreads();
    for (int off = 1; off < 256; off <<= 1) {
        int t = (threadIdx.x >= (unsigned)off) ? sh[threadIdx.x - off] : 0;
        __syncthreads();
        sh[threadIdx.x] += t;
        __syncthreads();
    }
    if (i < n) d[i] = sh[threadIdx.x];
    if (threadIdx.x == 255) bsum[blockIdx.x] = sh[255];
}

__global__ void k_scanb(int* __restrict__ bsum, int nb) {
    __shared__ int sh[256];
    __shared__ int carry;
    if (threadIdx.x == 0) carry = 0;
    __syncthreads();
    for (int base = 0; base < nb; base += 256) {
        int i = base + threadIdx.x;
        sh[threadIdx.x] = (i < nb) ? bsum[i] : 0;
        __syncthreads();
        for (int off = 1; off < 256; off <<= 1) {
            int t = (threadIdx.x >= (unsigned)off) ? sh[threadIdx.x - off] : 0;
            __syncthreads();
            sh[threadIdx.x] += t;
            __syncthreads();
        }
        if (i < nb) bsum[i] = sh[threadIdx.x] + carry;
        __syncthreads();
        if (threadIdx.x == 0) carry += sh[255];
        __syncthreads();
    }
}

__global__ void k_addoff(int* __restrict__ d, const int* __restrict__ bsum, int n) {
    int i = blockIdx.x * 256 + threadIdx.x;
    if (i < n && blockIdx.x > 0) d[i] += bsum[blockIdx.x - 1];
}

// atomic-free placement: pos = start(gs) + rank(e)
__global__ void k_place(Pats P, const int* __restrict__ rp, const int* __restrict__ rank,
                        int* __restrict__ vP) {
    int p = blockIdx.y;
    int e = blockIdx.x * blockDim.x + threadIdx.x;
    if (e >= P.E[p]) return;
    int gs = P.base[p] + P.seg[p][e];
    int pos = rp[gs] + rank[P.ebase[p] + e];   // rp[gs] = end(gs-1) = start(gs)
    vP[pos] = P.vidx[p][e];
}

// ---------------- MFMA matmul (bf16x3 split), bf16 Y output ----------------
__global__ void mm64_mfma(const float* __restrict__ X, const float* __restrict__ W,
                          const float* __restrict__ a, unsigned short* __restrict__ Yb,
                          float* __restrict__ p, float* __restrict__ q, int nchunk) {
    int lane = threadIdx.x & 63;
    int l15 = lane & 15, lq = lane >> 4;
    int wid = blockIdx.x * (blockDim.x >> 6) + (threadIdx.x >> 6);
    int nw = gridDim.x * (blockDim.x >> 6);

    short8 bh[4][2], bl[4][2];
#pragma unroll
    for (int t = 0; t < 4; ++t)
#pragma unroll
        for (int h = 0; h < 2; ++h) {
            const float* wp = W + (size_t)(h * 32 + lq * 8) * 64 + 16 * t + l15;
#pragma unroll
            for (int j = 0; j < 8; ++j) {
                float wv = wp[(size_t)j * 64];
                unsigned short hi = btop(wv);
                float rem = wv - __uint_as_float((unsigned)hi << 16);
                bh[t][h][j] = (short)hi;
                bl[t][h][j] = (short)btop(rem);
            }
        }
    float av0[4], av1[4];
#pragma unroll
    for (int t = 0; t < 4; ++t) {
        av0[t] = a[16 * t + l15];
        av1[t] = a[64 + 16 * t + l15];
    }

    for (int c = wid; c < nchunk; c += nw) {
        int base = c * 16;
        f32x4 acc[4];
#pragma unroll
        for (int t = 0; t < 4; ++t) acc[t] = (f32x4){0.f, 0.f, 0.f, 0.f};
#pragma unroll
        for (int h = 0; h < 2; ++h) {
            const f32x4* xp = (const f32x4*)(X + (size_t)(base + l15) * 64 + h * 32 + lq * 8);
            f32x4 x0 = xp[0], x1 = xp[1];
            short8 ah, al;
#pragma unroll
            for (int j = 0; j < 4; ++j) {
                unsigned short h0 = btop(x0[j]);
                float r0 = x0[j] - __uint_as_float((unsigned)h0 << 16);
                ah[j] = (short)h0;
                al[j] = (short)btop(r0);
                unsigned short h1 = btop(x1[j]);
                float r1 = x1[j] - __uint_as_float((unsigned)h1 << 16);
                ah[4 + j] = (short)h1;
                al[4 + j] = (short)btop(r1);
            }
#pragma unroll
            for (int t = 0; t < 4; ++t) {
                acc[t] = __builtin_amdgcn_mfma_f32_16x16x32_bf16(ah, bh[t][h], acc[t], 0, 0, 0);
                acc[t] = __builtin_amdgcn_mfma_f32_16x16x32_bf16(ah, bl[t][h], acc[t], 0, 0, 0);
                acc[t] = __builtin_amdgcn_mfma_f32_16x16x32_bf16(al, bh[t][h], acc[t], 0, 0, 0);
            }
        }
#pragma unroll
        for (int t = 0; t < 4; ++t)
#pragma unroll
            for (int r = 0; r < 4; ++r)
                Yb[(size_t)(base + lq * 4 + r) * 64 + 16 * t + l15] = f2bf(acc[t][r]);
#pragma unroll
        for (int r = 0; r < 4; ++r) {
            float pr = acc[0][r] * av0[0] + acc[1][r] * av0[1] + acc[2][r] * av0[2] + acc[3][r] * av0[3];
            float qr = acc[0][r] * av1[0] + acc[1][r] * av1[1] + acc[2][r] * av1[2] + acc[3][r] * av1[3];
#pragma unroll
            for (int off = 8; off; off >>= 1) {
                pr += __shfl_xor(pr, off, 64);
                qr += __shfl_xor(qr, off, 64);
            }
            if (l15 == 0) {
                p[base + lq * 4 + r] = pr;
                q[base + lq * 4 + r] = qr;
            }
        }
    }
}

// uu[j] = W[j,:]@a[0:64]; uu[64+j] = W[j,:]@a[64:128]   (1 block x 64)
__global__ void uvec_k(const float* __restrict__ W, const float* __restrict__ a2c,
                       float* __restrict__ uu) {
    int j = threadIdx.x;
    float s0 = 0.f, s1 = 0.f;
    for (int k = 0; k < 64; ++k) {
        float w = W[j * 64 + k];
        s0 = fmaf(w, a2c[k], s0);
        s1 = fmaf(w, a2c[64 + k], s1);
    }
    uu[j] = s0;
    uu[64 + j] = s1;
}

__global__ void proj2(const float* __restrict__ X, const float* __restrict__ uu,
                      float* __restrict__ p, float* __restrict__ q, int n) {
    int lane = threadIdx.x & 63;
    int row = blockIdx.x * (blockDim.x >> 6) + (threadIdx.x >> 6);
    if (row >= n) return;
    float xv = X[(size_t)row * 64 + lane];
    float a = xv * uu[lane];
    float b = xv * uu[64 + lane];
#pragma unroll
    for (int off = 32; off; off >>= 1) {
        a += __shfl_xor(a, off, 64);
        b += __shfl_xor(b, off, 64);
    }
    if (lane == 0) { p[row] = a; q[row] = b; }
}

// ---------------- segment attention gather (16 lanes/segment) ----------------
// non-destructive CSR: beg = rp_all[gs], end = rp_all[gs+1]
__device__ __forceinline__ void seg_gather(
    const int* __restrict__ rp_all, int base, int s, const int* __restrict__ vP,
    const float* __restrict__ ps, const float* __restrict__ pv,
    const unsigned short* __restrict__ Mb, int gl, int gbase, f32x4& acc) {
    int gs = base + s;
    int beg = rp_all[gs];
    int end = rp_all[gs + 1];
    int nE = end - beg;
    if (nE <= 0) return;
    float pss = ps[s];
    if (nE <= 16) {  // fast path
        int j = beg + gl;
        int v = (j < end) ? vP[j] : 0;
        float l = (j < end) ? lrelu(pss + pv[v]) : -3.4e38f;
        float mx = l;
#pragma unroll
        for (int off = 8; off; off >>= 1) mx = fmaxf(mx, __shfl_xor(mx, off, 64));
        float ev = (j < end) ? __expf(l - mx) : 0.f;
        float ssum = ev;
#pragma unroll
        for (int off = 8; off; off >>= 1) ssum += __shfl_xor(ssum, off, 64);
        float att = ev / ssum;
        for (int t0 = 0; t0 < nE; t0 += 4) {  // batched: 4 independent loads in flight
            float w0 = __shfl(att, gbase + t0, 64), w1 = __shfl(att, gbase + t0 + 1, 64);
            float w2 = __shfl(att, gbase + t0 + 2, 64), w3 = __shfl(att, gbase + t0 + 3, 64);
            int u0 = __shfl(v, gbase + t0, 64), u1 = __shfl(v, gbase + t0 + 1, 64);
            int u2 = __shfl(v, gbase + t0 + 2, 64), u3 = __shfl(v, gbase + t0 + 3, 64);
            u16x4 m0 = *(const u16x4*)(Mb + (size_t)u0 * 64 + gl * 4);
            u16x4 m1 = *(const u16x4*)(Mb + (size_t)u1 * 64 + gl * 4);
            u16x4 m2 = *(const u16x4*)(Mb + (size_t)u2 * 64 + gl * 4);
            u16x4 m3 = *(const u16x4*)(Mb + (size_t)u3 * 64 + gl * 4);
#pragma unroll
            for (int kk = 0; kk < 4; ++kk)
                acc[kk] += w0 * bf2f(m0[kk]) + w1 * bf2f(m1[kk]) +
                           w2 * bf2f(m2[kk]) + w3 * bf2f(m3[kk]);
        }
    } else {  // general path (rare long segments)
        float mx = -3.4e38f;
        for (int j0 = beg; j0 < end; j0 += 16) {
            int j = j0 + gl;
            float l = (j < end) ? lrelu(pss + pv[vP[j]]) : -3.4e38f;
            mx = fmaxf(mx, l);
        }
#pragma unroll
        for (int off = 8; off; off >>= 1) mx = fmaxf(mx, __shfl_xor(mx, off, 64));
        float ssum = 0.f;
        for (int j0 = beg; j0 < end; j0 += 16) {
            int j = j0 + gl;
            ssum += (j < end) ? __expf(lrelu(pss + pv[vP[j]]) - mx) : 0.f;
        }
#pragma unroll
        for (int off = 8; off; off >>= 1) ssum += __shfl_xor(ssum, off, 64);
        float inv = 1.f / ssum;
        for (int j0 = beg; j0 < end; j0 += 16) {
            int j = j0 + gl;
            int v = (j < end) ? vP[j] : 0;
            float ev = (j < end) ? __expf(lrelu(pss + pv[v]) - mx) * inv : 0.f;
            int cnt = min(16, end - j0);
            for (int t0 = 0; t0 < cnt; t0 += 4) {
                float w0 = __shfl(ev, gbase + t0, 64), w1 = __shfl(ev, gbase + t0 + 1, 64);
                float w2 = __shfl(ev, gbase + t0 + 2, 64), w3 = __shfl(ev, gbase + t0 + 3, 64);
                int u0 = __shfl(v, gbase + t0, 64), u1 = __shfl(v, gbase + t0 + 1, 64);
                int u2 = __shfl(v, gbase + t0 + 2, 64), u3 = __shfl(v, gbase + t0 + 3, 64);
                u16x4 m0 = *(const u16x4*)(Mb + (size_t)u0 * 64 + gl * 4);
                u16x4 m1 = *(const u16x4*)(Mb + (size_t)u1 * 64 + gl * 4);
                u16x4 m2 = *(const u16x4*)(Mb + (size_t)u2 * 64 + gl * 4);
                u16x4 m3 = *(const u16x4*)(Mb + (size_t)u3 * 64 + gl * 4);
#pragma unroll
                for (int kk = 0; kk < 4; ++kk)
                    acc[kk] += w0 * bf2f(m0[kk]) + w1 * bf2f(m1[kk]) +
                               w2 * bf2f(m2[kk]) + w3 * bf2f(m3[kk]);
            }
        }
    }
}

__global__ void k_attn1(const int* __restrict__ rp_all, int base, const int* __restrict__ vP,
                        const float* __restrict__ ps, const float* __restrict__ pv,
                        const unsigned short* __restrict__ Mb, float* __restrict__ out,
                        int nseg) {
    int lane = threadIdx.x & 63;
    int g = lane >> 4, gl = lane & 15, gbase = g << 4;
    int s = (blockIdx.x * (blockDim.x >> 6) + (threadIdx.x >> 6)) * 4 + g;
    if (s >= nseg) return;
    f32x4 acc = (f32x4){0.f, 0.f, 0.f, 0.f};
    seg_gather(rp_all, base, s, vP, ps, pv, Mb, gl, gbase, acc);
    *(f32x4*)(out + (size_t)s * 64 + gl * 4) = acc;
}

__global__ void k_attn2(const int* __restrict__ rp_all, int baseA, int baseB,
                        const int* __restrict__ vP,
                        const float* __restrict__ psA, const float* __restrict__ pvA,
                        const unsigned short* __restrict__ MbA,
                        const float* __restrict__ psB, const float* __restrict__ pvB,
                        const unsigned short* __restrict__ MbB,
                        float* __restrict__ out, int nseg) {
    int lane = threadIdx.x & 63;
    int g = lane >> 4, gl = lane & 15, gbase = g << 4;
    int s = (blockIdx.x * (blockDim.x >> 6) + (threadIdx.x >> 6)) * 4 + g;
    if (s >= nseg) return;
    f32x4 acc = (f32x4){0.f, 0.f, 0.f, 0.f};
    seg_gather(rp_all, baseA, s, vP, psA, pvA, MbA, gl, gbase, acc);
    seg_gather(rp_all, baseB, s, vP, psB, pvB, MbB, gl, gbase, acc);
    *(f32x4*)(out + (size_t)s * 64 + gl * 4) = acc;
}

extern "C" void kernel_launch(void* const* d_in, const int* in_sizes, int n_in,
                              void* d_out, int out_size, void* d_ws, size_t ws_size,
                              hipStream_t stream) {
    (void)in_sizes; (void)n_in; (void)ws_size; (void)out_size;
    const float* x0 = (const float*)d_in[0];
    const float* x1 = (const float*)d_in[1];
    const float* x2 = (const float*)d_in[2];
    const int* adj0r = (const int*)d_in[3];
    const int* adj0c = (const int*)d_in[4];
    const int* adj1r = (const int*)d_in[5];
    const int* adj1c = (const int*)d_in[6];
    const int* co2r = (const int*)d_in[7];
    const int* co2c = (const int*)d_in[8];
    const int* i1r = (const int*)d_in[9];
    const int* i1c = (const int*)d_in[10];
    const int* i2r = (const int*)d_in[11];
    const int* i2c = (const int*)d_in[12];
    const float* W_h0_l1 = (const float*)d_in[13];
    const float* W_h0_l2 = (const float*)d_in[14];
    const float* W_h1_l2 = (const float*)d_in[15];
    const float* W_h2_l2 = (const float*)d_in[16];
    const float* Ws01_l1 = (const float*)d_in[17];
    const float* Wt01_l1 = (const float*)d_in[18];
    const float* Ws12_l1 = (const float*)d_in[19];
    const float* Wt12_l1 = (const float*)d_in[20];
    const float* Ws01_l2 = (const float*)d_in[21];
    const float* Wt01_l2 = (const float*)d_in[22];
    const float* Ws12_l2 = (const float*)d_in[23];
    const float* Wt12_l2 = (const float*)d_in[24];
    const float* a_h0_l1 = (const float*)d_in[25];
    const float* a_h0_l2 = (const float*)d_in[26];
    const float* a_h1_l2 = (const float*)d_in[27];
    const float* a_h2_l2 = (const float*)d_in[28];
    const float* a01_l1 = (const float*)d_in[29];
    const float* a12_l1 = (const float*)d_in[30];
    const float* a01_l2 = (const float*)d_in[31];
    const float* a12_l2 = (const float*)d_in[32];

    // -------- workspace layout (~202 MB) --------
    float* fb = (float*)d_ws;
    float* t0 = fb;              float* t1 = t0 + 300000;
    float* t2 = t1 + 300000;     float* t3 = t2 + 300000;
    float* t4 = t3 + 300000;     float* t5 = t4 + 300000;
    float* t6 = t5 + 300000;     float* t7 = t6 + 300000;
    float* t8 = t7 + 300000;     float* t9 = t8 + 300000;
    float* t10 = t9 + 300000;    float* t11 = t10 + 300000;
    float* uu = t11 + 300000;    // 128
    unsigned short* YA = (unsigned short*)(uu + 128);   // [CN0*64]
    unsigned short* YB = YA + (size_t)CN0 * 64;         // [CN1*64]
    unsigned short* YC = YB + (size_t)CN1 * 64;         // [CN0*64]
    unsigned short* YD = YC + (size_t)CN0 * 64;         // [CN2*64]
    unsigned short* YE = YD + (size_t)CN2 * 64;         // [CN1*64]
    int* rp_all = (int*)(YE + (size_t)CN1 * 64);        // TOTSEG+1
    int* vP_all = rp_all + (TOTSEG + 1);                // TOTE
    int* rank_all = vP_all + TOTE;                      // TOTE
    int* bsum   = rank_all + TOTE;                      // 6144
    int* bsum2  = bsum + 6144;                          // 64

    float* r0 = (float*)d_out;
    float* r1 = r0 + (size_t)CN0 * 64;
    float* r2 = r1 + (size_t)CN1 * 64;

    // pattern bases: A0, E1, F1, E2, F2, A1, C2
    const int bA0 = 0;
    const int bE1 = CN0;
    const int bF1 = 2 * CN0;
    const int bE2 = 2 * CN0 + CN1;
    const int bF2 = 2 * CN0 + 2 * CN1;
    const int bA1 = 2 * CN0 + 2 * CN1 + CN2;
    const int bC2 = 2 * CN0 + 3 * CN1 + CN2;
    Pats P;
    P.seg[0] = adj0r; P.vidx[0] = adj0c; P.E[0] = EA0; P.base[0] = bA0;
    P.seg[1] = i1r;   P.vidx[1] = i1c;   P.E[1] = EB1; P.base[1] = bE1;
    P.seg[2] = i1c;   P.vidx[2] = i1r;   P.E[2] = EB1; P.base[2] = bF1;
    P.seg[3] = i2r;   P.vidx[3] = i2c;   P.E[3] = EB2; P.base[3] = bE2;
    P.seg[4] = i2c;   P.vidx[4] = i2r;   P.E[4] = EB2; P.base[4] = bF2;
    P.seg[5] = adj1r; P.vidx[5] = adj1c; P.E[5] = EA1; P.base[5] = bA1;
    P.seg[6] = co2r;  P.vidx[6] = co2c;  P.E[6] = EC2; P.base[6] = bC2;
    int eb = 0;
    for (int p = 0; p < 7; ++p) { P.ebase[p] = eb; eb += P.E[p]; }
    const int Emax = EA1;

    auto MMF = [&](const float* X, const float* W, const float* a, unsigned short* Yb,
                   float* p, float* q, int n) {
        int nchunk = n / 16;
        int blocks = min(1024, (nchunk + 3) / 4);
        mm64_mfma<<<dim3(blocks), dim3(256), 0, stream>>>(X, W, a, Yb, p, q, nchunk);
    };
    auto PROJ = [&](const float* X, const float* W, const float* a2, float* p, float* q, int n) {
        uvec_k<<<dim3(1), dim3(64), 0, stream>>>(W, a2, uu);
        proj2<<<dim3((n + 3) / 4), dim3(256), 0, stream>>>(X, uu, p, q, n);
    };
    auto AGG1 = [&](int base, const float* ps, const float* pv, const unsigned short* Mb,
                    float* out, int nseg) {
        k_attn1<<<dim3((nseg + 15) / 16), dim3(256), 0, stream>>>(
            rp_all, base, vP_all, ps, pv, Mb, out, nseg);
    };
    auto AGG2 = [&](int baseA, const float* psA, const float* pvA, const unsigned short* MbA,
                    int baseB, const float* psB, const float* pvB, const unsigned short* MbB,
                    float* out, int nseg) {
        k_attn2<<<dim3((nseg + 15) / 16), dim3(256), 0, stream>>>(
            rp_all, baseA, baseB, vP_all, psA, pvA, MbA, psB, pvB, MbB, out, nseg);
    };

    // ======== fused CSR build: histogram+rank, scan, atomic-free place ========
    hipMemsetAsync(rp_all, 0, (size_t)(TOTSEG + 1) * 4, stream);
    {
        dim3 gh((Emax + 255) / 256, 7);
        k_histrank<<<gh, dim3(256), 0, stream>>>(P, rp_all + 1, rank_all);
        int nb = (TOTSEG + 255) / 256;       // 5860
        int nb2 = (nb + 255) / 256;          // 23
        k_blkscan<<<dim3(nb), dim3(256), 0, stream>>>(rp_all + 1, TOTSEG, bsum);
        k_blkscan<<<dim3(nb2), dim3(256), 0, stream>>>(bsum, nb, bsum2);
        k_scanb<<<dim3(1), dim3(256), 0, stream>>>(bsum2, nb2);
        k_addoff<<<dim3(nb2), dim3(256), 0, stream>>>(bsum, bsum2, nb);
        k_addoff<<<dim3(nb), dim3(256), 0, stream>>>(rp_all + 1, bsum, TOTSEG);
        k_place<<<gh, dim3(256), 0, stream>>>(P, rp_all, rank_all, vP_all);
    }

    // ======== LEVEL 1: all projections, then fused aggregations ========
    MMF(x0, W_h0_l1, a_h0_l1, YA, t0, t1, CN0);    // m0;   p,q
    MMF(x1, Ws01_l1, a01_l1, YB, t2, t3, CN1);     // sm01; ps,qs
    MMF(x0, Wt01_l1, a01_l1, YC, t4, t5, CN0);     // tm01; pt,qt
    MMF(x2, Ws12_l1, a12_l1, YD, t6, t7, CN2);     // sm12; ps,qs
    MMF(x1, Wt12_l1, a12_l1, YE, t8, t9, CN1);     // tm12; pt,qt
    AGG2(bA0, t0, t1, YA, bE1, t5, t2, YB, r0, CN0);   // x_0_to_0 + x_1_to_0
    AGG2(bF1, t3, t4, YC, bE2, t9, t6, YD, r1, CN1);   // x_0_to_1 + x_2_to_1
    AGG1(bF2, t7, t8, YE, r2, CN2);                    // x_1_to_2

    // ======== LEVEL 2: all projections (read r*), then aggregations (write r*) ====
    MMF(r0, W_h0_l2, a_h0_l2, YA, t0, t1, CN0);    // m00
    MMF(r0, Wt01_l2, a01_l2, YC, t4, t11, CN0);    // tm01; pt01->t4
    MMF(r1, W_h1_l2, a_h1_l2, YB, t2, t3, CN1);    // m11
    MMF(r1, Wt12_l2, a12_l2, YE, t8, t11, CN1);    // tm12; pt12->t8
    PROJ(r1, Ws01_l2, a01_l2, t11, t6, CN1);       // qs01->t6
    MMF(r2, W_h2_l2, a_h2_l2, YD, t7, t9, CN2);    // m22
    PROJ(r2, Ws12_l2, a12_l2, t11, t10, CN2);      // qs12->t10
    AGG1(bA0, t0, t1, YA, r0, CN0);                          // x_0_out
    AGG2(bA1, t2, t3, YB, bF1, t6, t4, YC, r1, CN1);         // x_1_to_1 + x_0_to_1
    AGG2(bC2, t7, t9, YD, bF2, t10, t8, YE, r2, CN2);        // x_2_to_2 + x_1_to_2
}

// Round 10
// 815.958 us; speedup vs baseline: 1.4874x; 1.1017x over previous
//
#include <hip/hip_runtime.h>

#define CN0 100000
#define CN1 300000
#define CN2 200000
#define EA0 600000
#define EA1 1200000
#define EC2 600000
#define EB1 600000
#define EB2 600000
#define TOTSEG (2*CN0 + 3*CN1 + 2*CN2)           // 1,500,000
#define TOTE   (EA0 + EA1 + EC2 + 2*EB1 + 2*EB2) // 6,600,000

typedef __attribute__((ext_vector_type(8))) short short8;
typedef __attribute__((ext_vector_type(4))) float f32x4;
typedef __attribute__((ext_vector_type(4))) unsigned short u16x4;

__device__ __forceinline__ float lrelu(float v) { return v >= 0.f ? v : 0.2f * v; }
__device__ __forceinline__ unsigned short btop(float x) {
    return (unsigned short)(__float_as_uint(x) >> 16);
}
__device__ __forceinline__ unsigned short f2bf(float x) {  // RTN f32->bf16
    unsigned u = __float_as_uint(x);
    return (unsigned short)((u + 0x7FFFu + ((u >> 16) & 1u)) >> 16);
}
__device__ __forceinline__ float bf2f(unsigned short b) {
    return __uint_as_float((unsigned)b << 16);
}

struct Pats {
    const int* seg[7];
    const int* vidx[7];
    int E[7];
    int base[7];
    int ebase[7];
};

struct MMJob {
    const float* X; const float* W; const float* a;
    unsigned short* Y; float* p; float* q; int nchunk;
};

// ---------------- shared single-W MFMA body (bf16x3 split) ----------------
__device__ __forceinline__ void mm_body(const float* __restrict__ X, const float* __restrict__ W,
                                        const float* __restrict__ a, unsigned short* __restrict__ Yb,
                                        float* __restrict__ p, float* __restrict__ q,
                                        int nchunk, int wid, int nw, int lane) {
    int l15 = lane & 15, lq = lane >> 4;
    short8 bh[4][2], bl[4][2];
#pragma unroll
    for (int t = 0; t < 4; ++t)
#pragma unroll
        for (int h = 0; h < 2; ++h) {
            const float* wp = W + (size_t)(h * 32 + lq * 8) * 64 + 16 * t + l15;
#pragma unroll
            for (int j = 0; j < 8; ++j) {
                float wv = wp[(size_t)j * 64];
                unsigned short hi = btop(wv);
                float rem = wv - __uint_as_float((unsigned)hi << 16);
                bh[t][h][j] = (short)hi;
                bl[t][h][j] = (short)btop(rem);
            }
        }
    float av0[4], av1[4];
#pragma unroll
    for (int t = 0; t < 4; ++t) {
        av0[t] = a[16 * t + l15];
        av1[t] = a[64 + 16 * t + l15];
    }
    for (int c = wid; c < nchunk; c += nw) {
        int base = c * 16;
        f32x4 acc[4];
#pragma unroll
        for (int t = 0; t < 4; ++t) acc[t] = (f32x4){0.f, 0.f, 0.f, 0.f};
#pragma unroll
        for (int h = 0; h < 2; ++h) {
            const f32x4* xp = (const f32x4*)(X + (size_t)(base + l15) * 64 + h * 32 + lq * 8);
            f32x4 x0 = xp[0], x1 = xp[1];
            short8 ah, al;
#pragma unroll
            for (int j = 0; j < 4; ++j) {
                unsigned short h0 = btop(x0[j]);
                float r0 = x0[j] - __uint_as_float((unsigned)h0 << 16);
                ah[j] = (short)h0;
                al[j] = (short)btop(r0);
                unsigned short h1 = btop(x1[j]);
                float r1 = x1[j] - __uint_as_float((unsigned)h1 << 16);
                ah[4 + j] = (short)h1;
                al[4 + j] = (short)btop(r1);
            }
#pragma unroll
            for (int t = 0; t < 4; ++t) {
                acc[t] = __builtin_amdgcn_mfma_f32_16x16x32_bf16(ah, bh[t][h], acc[t], 0, 0, 0);
                acc[t] = __builtin_amdgcn_mfma_f32_16x16x32_bf16(ah, bl[t][h], acc[t], 0, 0, 0);
                acc[t] = __builtin_amdgcn_mfma_f32_16x16x32_bf16(al, bh[t][h], acc[t], 0, 0, 0);
            }
        }
#pragma unroll
        for (int t = 0; t < 4; ++t)
#pragma unroll
            for (int r = 0; r < 4; ++r)
                Yb[(size_t)(base + lq * 4 + r) * 64 + 16 * t + l15] = f2bf(acc[t][r]);
#pragma unroll
        for (int r = 0; r < 4; ++r) {
            float pr = acc[0][r] * av0[0] + acc[1][r] * av0[1] + acc[2][r] * av0[2] + acc[3][r] * av0[3];
            float qr = acc[0][r] * av1[0] + acc[1][r] * av1[1] + acc[2][r] * av1[2] + acc[3][r] * av1[3];
#pragma unroll
            for (int off = 8; off; off >>= 1) {
                pr += __shfl_xor(pr, off, 64);
                qr += __shfl_xor(qr, off, 64);
            }
            if (l15 == 0) {
                p[base + lq * 4 + r] = pr;
                q[base + lq * 4 + r] = qr;
            }
        }
    }
}

// ---------------- mega kernel: 5 MMF roles + histogram+rank role ----------------
__global__ __launch_bounds__(256) void k_l1_fused(
        MMJob j0, MMJob j1, MMJob j2, MMJob j3, MMJob j4,
        Pats P, int* __restrict__ rp1, int* __restrict__ rank, int mmBlocks) {
    int b = blockIdx.x;
    int nm = 5 * mmBlocks;
    int lane = threadIdx.x & 63;
    if (b < nm) {
        int role = b / mmBlocks, rb = b - role * mmBlocks;
        MMJob J = (role == 0) ? j0 : (role == 1) ? j1 : (role == 2) ? j2
                : (role == 3) ? j3 : j4;
        int wid = rb * (blockDim.x >> 6) + (threadIdx.x >> 6);
        int nw = mmBlocks * (blockDim.x >> 6);
        mm_body(J.X, J.W, J.a, J.Y, J.p, J.q, J.nchunk, wid, nw, lane);
    } else {
        int hb = b - nm;
        int pidx = 0, acc = 0;
        for (; pidx < 7; ++pidx) {
            int pb = (P.E[pidx] + 255) >> 8;
            if (hb < acc + pb) break;
            acc += pb;
        }
        if (pidx >= 7) return;
        int e = (hb - acc) * 256 + threadIdx.x;
        if (e >= P.E[pidx]) return;
        int gs = P.base[pidx] + P.seg[pidx][e];
        rank[P.ebase[pidx] + e] = atomicAdd(&rp1[gs], 1);
    }
}

// ---------------- scan / place ----------------

__global__ void k_blkscan(int* __restrict__ d, int n, int* __restrict__ bsum) {
    __shared__ int sh[256];
    int i = blockIdx.x * 256 + threadIdx.x;
    sh[threadIdx.x] = (i < n) ? d[i] : 0;
    __syncthreads();
    for (int off = 1; off < 256; off <<= 1) {
        int t = (threadIdx.x >= (unsigned)off) ? sh[threadIdx.x - off] : 0;
        __syncthreads();
        sh[threadIdx.x] += t;
        __syncthreads();
    }
    if (i < n) d[i] = sh[threadIdx.x];
    if (threadIdx.x == 255) bsum[blockIdx.x] = sh[255];
}

__global__ void k_scanb(int* __restrict__ bsum, int nb) {
    __shared__ int sh[256];
    __shared__ int carry;
    if (threadIdx.x == 0) carry = 0;
    __syncthreads();
    for (int base = 0; base < nb; base += 256) {
        int i = base + threadIdx.x;
        sh[threadIdx.x] = (i < nb) ? bsum[i] : 0;
        __syncthreads();
        for (int off = 1; off < 256; off <<= 1) {
            int t = (threadIdx.x >= (unsigned)off) ? sh[threadIdx.x - off] : 0;
            __syncthreads();
            sh[threadIdx.x] += t;
            __syncthreads();
        }
        if (i < nb) bsum[i] = sh[threadIdx.x] + carry;
        __syncthreads();
        if (threadIdx.x == 0) carry += sh[255];
        __syncthreads();
    }
}

__global__ void k_addoff(int* __restrict__ d, const int* __restrict__ bsum, int n) {
    int i = blockIdx.x * 256 + threadIdx.x;
    if (i < n && blockIdx.x > 0) d[i] += bsum[blockIdx.x - 1];
}

// atomic-free placement: pos = start(gs) + rank(e)
__global__ void k_place(Pats P, const int* __restrict__ rp, const int* __restrict__ rank,
                        int* __restrict__ vP) {
    int p = blockIdx.y;
    int e = blockIdx.x * blockDim.x + threadIdx.x;
    if (e >= P.E[p]) return;
    int gs = P.base[p] + P.seg[p][e];
    int pos = rp[gs] + rank[P.ebase[p] + e];
    vP[pos] = P.vidx[p][e];
}

// ---------------- dual-W / vec-proj fused MFMA kernel (L2) ----------------
template <int DUAL, int VEC>
__global__ __launch_bounds__(256) void mm64_t(
        const float* __restrict__ X,
        const float* __restrict__ W1, const float* __restrict__ a1,
        unsigned short* __restrict__ Y1, float* __restrict__ p1, float* __restrict__ q1,
        const float* __restrict__ W2, const float* __restrict__ a2,
        unsigned short* __restrict__ Y2, float* __restrict__ p2, float* __restrict__ q2,
        const float* __restrict__ uuv, float* __restrict__ pv, int nchunk) {
    int lane = threadIdx.x & 63;
    int l15 = lane & 15, lq = lane >> 4;
    int wid = blockIdx.x * (blockDim.x >> 6) + (threadIdx.x >> 6);
    int nw = gridDim.x * (blockDim.x >> 6);

    short8 b1h[4][2], b1l[4][2], b2h[4][2], b2l[4][2];
#pragma unroll
    for (int t = 0; t < 4; ++t)
#pragma unroll
        for (int h = 0; h < 2; ++h) {
            const float* wp = W1 + (size_t)(h * 32 + lq * 8) * 64 + 16 * t + l15;
#pragma unroll
            for (int j = 0; j < 8; ++j) {
                float wv = wp[(size_t)j * 64];
                unsigned short hi = btop(wv);
                float rem = wv - __uint_as_float((unsigned)hi << 16);
                b1h[t][h][j] = (short)hi;
                b1l[t][h][j] = (short)btop(rem);
            }
        }
    if (DUAL) {
#pragma unroll
        for (int t = 0; t < 4; ++t)
#pragma unroll
            for (int h = 0; h < 2; ++h) {
                const float* wp = W2 + (size_t)(h * 32 + lq * 8) * 64 + 16 * t + l15;
#pragma unroll
                for (int j = 0; j < 8; ++j) {
                    float wv = wp[(size_t)j * 64];
                    unsigned short hi = btop(wv);
                    float rem = wv - __uint_as_float((unsigned)hi << 16);
                    b2h[t][h][j] = (short)hi;
                    b2l[t][h][j] = (short)btop(rem);
                }
            }
    }
    float a10[4], a11[4], a20[4], a21[4];
#pragma unroll
    for (int t = 0; t < 4; ++t) {
        a10[t] = a1[16 * t + l15];
        a11[t] = a1[64 + 16 * t + l15];
        if (DUAL) { a20[t] = a2[16 * t + l15]; a21[t] = a2[64 + 16 * t + l15]; }
    }
    float uv[16];
    if (VEC) {
#pragma unroll
        for (int h = 0; h < 2; ++h)
#pragma unroll
            for (int j = 0; j < 8; ++j) uv[h * 8 + j] = uuv[h * 32 + lq * 8 + j];
    }

    for (int c = wid; c < nchunk; c += nw) {
        int base = c * 16;
        f32x4 acc1[4], acc2[4];
#pragma unroll
        for (int t = 0; t < 4; ++t) {
            acc1[t] = (f32x4){0.f, 0.f, 0.f, 0.f};
            if (DUAL) acc2[t] = (f32x4){0.f, 0.f, 0.f, 0.f};
        }
        float vp = 0.f;
#pragma unroll
        for (int h = 0; h < 2; ++h) {
            const f32x4* xp = (const f32x4*)(X + (size_t)(base + l15) * 64 + h * 32 + lq * 8);
            f32x4 x0 = xp[0], x1 = xp[1];
            if (VEC) {
#pragma unroll
                for (int j = 0; j < 4; ++j)
                    vp += x0[j] * uv[h * 8 + j] + x1[j] * uv[h * 8 + 4 + j];
            }
            short8 ah, al;
#pragma unroll
            for (int j = 0; j < 4; ++j) {
                unsigned short h0 = btop(x0[j]);
                float r0 = x0[j] - __uint_as_float((unsigned)h0 << 16);
                ah[j] = (short)h0;
                al[j] = (short)btop(r0);
                unsigned short h1 = btop(x1[j]);
                float r1 = x1[j] - __uint_as_float((unsigned)h1 << 16);
                ah[4 + j] = (short)h1;
                al[4 + j] = (short)btop(r1);
            }
#pragma unroll
            for (int t = 0; t < 4; ++t) {
                acc1[t] = __builtin_amdgcn_mfma_f32_16x16x32_bf16(ah, b1h[t][h], acc1[t], 0, 0, 0);
                acc1[t] = __builtin_amdgcn_mfma_f32_16x16x32_bf16(ah, b1l[t][h], acc1[t], 0, 0, 0);
                acc1[t] = __builtin_amdgcn_mfma_f32_16x16x32_bf16(al, b1h[t][h], acc1[t], 0, 0, 0);
                if (DUAL) {
                    acc2[t] = __builtin_amdgcn_mfma_f32_16x16x32_bf16(ah, b2h[t][h], acc2[t], 0, 0, 0);
                    acc2[t] = __builtin_amdgcn_mfma_f32_16x16x32_bf16(ah, b2l[t][h], acc2[t], 0, 0, 0);
                    acc2[t] = __builtin_amdgcn_mfma_f32_16x16x32_bf16(al, b2h[t][h], acc2[t], 0, 0, 0);
                }
            }
        }
#pragma unroll
        for (int t = 0; t < 4; ++t)
#pragma unroll
            for (int r = 0; r < 4; ++r) {
                Y1[(size_t)(base + lq * 4 + r) * 64 + 16 * t + l15] = f2bf(acc1[t][r]);
                if (DUAL) Y2[(size_t)(base + lq * 4 + r) * 64 + 16 * t + l15] = f2bf(acc2[t][r]);
            }
#pragma unroll
        for (int r = 0; r < 4; ++r) {
            float pr = acc1[0][r] * a10[0] + acc1[1][r] * a10[1] + acc1[2][r] * a10[2] + acc1[3][r] * a10[3];
            float qr = acc1[0][r] * a11[0] + acc1[1][r] * a11[1] + acc1[2][r] * a11[2] + acc1[3][r] * a11[3];
#pragma unroll
            for (int off = 8; off; off >>= 1) {
                pr += __shfl_xor(pr, off, 64);
                qr += __shfl_xor(qr, off, 64);
            }
            if (l15 == 0) {
                p1[base + lq * 4 + r] = pr;
                q1[base + lq * 4 + r] = qr;
            }
            if (DUAL) {
                float pr2 = acc2[0][r] * a20[0] + acc2[1][r] * a20[1] + acc2[2][r] * a20[2] + acc2[3][r] * a20[3];
                float qr2 = acc2[0][r] * a21[0] + acc2[1][r] * a21[1] + acc2[2][r] * a21[2] + acc2[3][r] * a21[3];
#pragma unroll
                for (int off = 8; off; off >>= 1) {
                    pr2 += __shfl_xor(pr2, off, 64);
                    qr2 += __shfl_xor(qr2, off, 64);
                }
                if (l15 == 0) {
                    p2[base + lq * 4 + r] = pr2;
                    q2[base + lq * 4 + r] = qr2;
                }
            }
        }
        if (VEC) {
            vp += __shfl_xor(vp, 16, 64);
            vp += __shfl_xor(vp, 32, 64);
            if (lane < 16) pv[base + l15] = vp;
        }
    }
}

// uu[j] = W[j,:]@a[0:64]; uu[64+j] = W[j,:]@a[64:128]   (1 block x 64)
__global__ void uvec_k(const float* __restrict__ W, const float* __restrict__ a2c,
                       float* __restrict__ uu) {
    int j = threadIdx.x;
    float s0 = 0.f, s1 = 0.f;
    for (int k = 0; k < 64; ++k) {
        float w = W[j * 64 + k];
        s0 = fmaf(w, a2c[k], s0);
        s1 = fmaf(w, a2c[64 + k], s1);
    }
    uu[j] = s0;
    uu[64 + j] = s1;
}

// ---------------- segment attention gather (16 lanes/segment) ----------------
__device__ __forceinline__ void seg_gather(
    const int* __restrict__ rp_all, int base, int s, const int* __restrict__ vP,
    const float* __restrict__ ps, const float* __restrict__ pv,
    const unsigned short* __restrict__ Mb, int gl, int gbase, f32x4& acc) {
    int gs = base + s;
    int beg = rp_all[gs];
    int end = rp_all[gs + 1];
    int nE = end - beg;
    if (nE <= 0) return;
    float pss = ps[s];
    if (nE <= 16) {  // fast path
        int j = beg + gl;
        int v = (j < end) ? vP[j] : 0;
        float l = (j < end) ? lrelu(pss + pv[v]) : -3.4e38f;
        float mx = l;
#pragma unroll
        for (int off = 8; off; off >>= 1) mx = fmaxf(mx, __shfl_xor(mx, off, 64));
        float ev = (j < end) ? __expf(l - mx) : 0.f;
        float ssum = ev;
#pragma unroll
        for (int off = 8; off; off >>= 1) ssum += __shfl_xor(ssum, off, 64);
        float att = ev / ssum;
        for (int t0 = 0; t0 < nE; t0 += 4) {
            float w0 = __shfl(att, gbase + t0, 64), w1 = __shfl(att, gbase + t0 + 1, 64);
            float w2 = __shfl(att, gbase + t0 + 2, 64), w3 = __shfl(att, gbase + t0 + 3, 64);
            int u0 = __shfl(v, gbase + t0, 64), u1 = __shfl(v, gbase + t0 + 1, 64);
            int u2 = __shfl(v, gbase + t0 + 2, 64), u3 = __shfl(v, gbase + t0 + 3, 64);
            u16x4 m0 = *(const u16x4*)(Mb + (size_t)u0 * 64 + gl * 4);
            u16x4 m1 = *(const u16x4*)(Mb + (size_t)u1 * 64 + gl * 4);
            u16x4 m2 = *(const u16x4*)(Mb + (size_t)u2 * 64 + gl * 4);
            u16x4 m3 = *(const u16x4*)(Mb + (size_t)u3 * 64 + gl * 4);
#pragma unroll
            for (int kk = 0; kk < 4; ++kk)
                acc[kk] += w0 * bf2f(m0[kk]) + w1 * bf2f(m1[kk]) +
                           w2 * bf2f(m2[kk]) + w3 * bf2f(m3[kk]);
        }
    } else {  // general path (rare long segments)
        float mx = -3.4e38f;
        for (int j0 = beg; j0 < end; j0 += 16) {
            int j = j0 + gl;
            float l = (j < end) ? lrelu(pss + pv[vP[j]]) : -3.4e38f;
            mx = fmaxf(mx, l);
        }
#pragma unroll
        for (int off = 8; off; off >>= 1) mx = fmaxf(mx, __shfl_xor(mx, off, 64));
        float ssum = 0.f;
        for (int j0 = beg; j0 < end; j0 += 16) {
            int j = j0 + gl;
            ssum += (j < end) ? __expf(lrelu(pss + pv[vP[j]]) - mx) : 0.f;
        }
#pragma unroll
        for (int off = 8; off; off >>= 1) ssum += __shfl_xor(ssum, off, 64);
        float inv = 1.f / ssum;
        for (int j0 = beg; j0 < end; j0 += 16) {
            int j = j0 + gl;
            int v = (j < end) ? vP[j] : 0;
            float ev = (j < end) ? __expf(lrelu(pss + pv[v]) - mx) * inv : 0.f;
            int cnt = min(16, end - j0);
            for (int t0 = 0; t0 < cnt; t0 += 4) {
                float w0 = __shfl(ev, gbase + t0, 64), w1 = __shfl(ev, gbase + t0 + 1, 64);
                float w2 = __shfl(ev, gbase + t0 + 2, 64), w3 = __shfl(ev, gbase + t0 + 3, 64);
                int u0 = __shfl(v, gbase + t0, 64), u1 = __shfl(v, gbase + t0 + 1, 64);
                int u2 = __shfl(v, gbase + t0 + 2, 64), u3 = __shfl(v, gbase + t0 + 3, 64);
                u16x4 m0 = *(const u16x4*)(Mb + (size_t)u0 * 64 + gl * 4);
                u16x4 m1 = *(const u16x4*)(Mb + (size_t)u1 * 64 + gl * 4);
                u16x4 m2 = *(const u16x4*)(Mb + (size_t)u2 * 64 + gl * 4);
                u16x4 m3 = *(const u16x4*)(Mb + (size_t)u3 * 64 + gl * 4);
#pragma unroll
                for (int kk = 0; kk < 4; ++kk)
                    acc[kk] += w0 * bf2f(m0[kk]) + w1 * bf2f(m1[kk]) +
                               w2 * bf2f(m2[kk]) + w3 * bf2f(m3[kk]);
            }
        }
    }
}

__global__ void k_attn1(const int* __restrict__ rp_all, int base, const int* __restrict__ vP,
                        const float* __restrict__ ps, const float* __restrict__ pv,
                        const unsigned short* __restrict__ Mb, float* __restrict__ out,
                        int nseg) {
    int lane = threadIdx.x & 63;
    int g = lane >> 4, gl = lane & 15, gbase = g << 4;
    int s = (blockIdx.x * (blockDim.x >> 6) + (threadIdx.x >> 6)) * 4 + g;
    if (s >= nseg) return;
    f32x4 acc = (f32x4){0.f, 0.f, 0.f, 0.f};
    seg_gather(rp_all, base, s, vP, ps, pv, Mb, gl, gbase, acc);
    *(f32x4*)(out + (size_t)s * 64 + gl * 4) = acc;
}

__global__ void k_attn2(const int* __restrict__ rp_all, int baseA, int baseB,
                        const int* __restrict__ vP,
                        const float* __restrict__ psA, const float* __restrict__ pvA,
                        const unsigned short* __restrict__ MbA,
                        const float* __restrict__ psB, const float* __restrict__ pvB,
                        const unsigned short* __restrict__ MbB,
                        float* __restrict__ out, int nseg) {
    int lane = threadIdx.x & 63;
    int g = lane >> 4, gl = lane & 15, gbase = g << 4;
    int s = (blockIdx.x * (blockDim.x >> 6) + (threadIdx.x >> 6)) * 4 + g;
    if (s >= nseg) return;
    f32x4 acc = (f32x4){0.f, 0.f, 0.f, 0.f};
    seg_gather(rp_all, baseA, s, vP, psA, pvA, MbA, gl, gbase, acc);
    seg_gather(rp_all, baseB, s, vP, psB, pvB, MbB, gl, gbase, acc);
    *(f32x4*)(out + (size_t)s * 64 + gl * 4) = acc;
}

extern "C" void kernel_launch(void* const* d_in, const int* in_sizes, int n_in,
                              void* d_out, int out_size, void* d_ws, size_t ws_size,
                              hipStream_t stream) {
    (void)in_sizes; (void)n_in; (void)ws_size; (void)out_size;
    const float* x0 = (const float*)d_in[0];
    const float* x1 = (const float*)d_in[1];
    const float* x2 = (const float*)d_in[2];
    const int* adj0r = (const int*)d_in[3];
    const int* adj0c = (const int*)d_in[4];
    const int* adj1r = (const int*)d_in[5];
    const int* adj1c = (const int*)d_in[6];
    const int* co2r = (const int*)d_in[7];
    const int* co2c = (const int*)d_in[8];
    const int* i1r = (const int*)d_in[9];
    const int* i1c = (const int*)d_in[10];
    const int* i2r = (const int*)d_in[11];
    const int* i2c = (const int*)d_in[12];
    const float* W_h0_l1 = (const float*)d_in[13];
    const float* W_h0_l2 = (const float*)d_in[14];
    const float* W_h1_l2 = (const float*)d_in[15];
    const float* W_h2_l2 = (const float*)d_in[16];
    const float* Ws01_l1 = (const float*)d_in[17];
    const float* Wt01_l1 = (const float*)d_in[18];
    const float* Ws12_l1 = (const float*)d_in[19];
    const float* Wt12_l1 = (const float*)d_in[20];
    const float* Ws01_l2 = (const float*)d_in[21];
    const float* Wt01_l2 = (const float*)d_in[22];
    const float* Ws12_l2 = (const float*)d_in[23];
    const float* Wt12_l2 = (const float*)d_in[24];
    const float* a_h0_l1 = (const float*)d_in[25];
    const float* a_h0_l2 = (const float*)d_in[26];
    const float* a_h1_l2 = (const float*)d_in[27];
    const float* a_h2_l2 = (const float*)d_in[28];
    const float* a01_l1 = (const float*)d_in[29];
    const float* a12_l1 = (const float*)d_in[30];
    const float* a01_l2 = (const float*)d_in[31];
    const float* a12_l2 = (const float*)d_in[32];

    // -------- workspace layout (~202 MB) --------
    float* fb = (float*)d_ws;
    float* t0 = fb;              float* t1 = t0 + 300000;
    float* t2 = t1 + 300000;     float* t3 = t2 + 300000;
    float* t4 = t3 + 300000;     float* t5 = t4 + 300000;
    float* t6 = t5 + 300000;     float* t7 = t6 + 300000;
    float* t8 = t7 + 300000;     float* t9 = t8 + 300000;
    float* t10 = t9 + 300000;    float* t11 = t10 + 300000;
    float* uuA = t11 + 300000;   // 128
    float* uuB = uuA + 128;      // 128
    unsigned short* YA = (unsigned short*)(uuB + 128);  // [CN0*64]
    unsigned short* YB = YA + (size_t)CN0 * 64;         // [CN1*64]
    unsigned short* YC = YB + (size_t)CN1 * 64;         // [CN0*64]
    unsigned short* YD = YC + (size_t)CN0 * 64;         // [CN2*64]
    unsigned short* YE = YD + (size_t)CN2 * 64;         // [CN1*64]
    int* rp_all = (int*)(YE + (size_t)CN1 * 64);        // TOTSEG+1
    int* vP_all = rp_all + (TOTSEG + 1);                // TOTE
    int* rank_all = vP_all + TOTE;                      // TOTE
    int* bsum   = rank_all + TOTE;                      // 6144
    int* bsum2  = bsum + 6144;                          // 64

    float* r0 = (float*)d_out;
    float* r1 = r0 + (size_t)CN0 * 64;
    float* r2 = r1 + (size_t)CN1 * 64;

    // pattern bases: A0, E1, F1, E2, F2, A1, C2
    const int bA0 = 0;
    const int bE1 = CN0;
    const int bF1 = 2 * CN0;
    const int bE2 = 2 * CN0 + CN1;
    const int bF2 = 2 * CN0 + 2 * CN1;
    const int bA1 = 2 * CN0 + 2 * CN1 + CN2;
    const int bC2 = 2 * CN0 + 3 * CN1 + CN2;
    Pats P;
    P.seg[0] = adj0r; P.vidx[0] = adj0c; P.E[0] = EA0; P.base[0] = bA0;
    P.seg[1] = i1r;   P.vidx[1] = i1c;   P.E[1] = EB1; P.base[1] = bE1;
    P.seg[2] = i1c;   P.vidx[2] = i1r;   P.E[2] = EB1; P.base[2] = bF1;
    P.seg[3] = i2r;   P.vidx[3] = i2c;   P.E[3] = EB2; P.base[3] = bE2;
    P.seg[4] = i2c;   P.vidx[4] = i2r;   P.E[4] = EB2; P.base[4] = bF2;
    P.seg[5] = adj1r; P.vidx[5] = adj1c; P.E[5] = EA1; P.base[5] = bA1;
    P.seg[6] = co2r;  P.vidx[6] = co2c;  P.E[6] = EC2; P.base[6] = bC2;
    int eb = 0, histBlocks = 0;
    for (int p = 0; p < 7; ++p) {
        P.ebase[p] = eb;
        eb += P.E[p];
        histBlocks += (P.E[p] + 255) / 256;
    }
    const int Emax = EA1;

    auto AGG1 = [&](int base, const float* ps, const float* pv, const unsigned short* Mb,
                    float* out, int nseg) {
        k_attn1<<<dim3((nseg + 15) / 16), dim3(256), 0, stream>>>(
            rp_all, base, vP_all, ps, pv, Mb, out, nseg);
    };
    auto AGG2 = [&](int baseA, const float* psA, const float* pvA, const unsigned short* MbA,
                    int baseB, const float* psB, const float* pvB, const unsigned short* MbB,
                    float* out, int nseg) {
        k_attn2<<<dim3((nseg + 15) / 16), dim3(256), 0, stream>>>(
            rp_all, baseA, baseB, vP_all, psA, pvA, MbA, psB, pvB, MbB, out, nseg);
    };

    // ======== mega kernel: histogram+rank co-launched with all 5 L1 matmuls ========
    hipMemsetAsync(rp_all, 0, (size_t)(TOTSEG + 1) * 4, stream);
    {
        const int mmBlocks = 96;
        MMJob j0 = {x0, W_h0_l1, a_h0_l1, YA, t0, t1, CN0 / 16};
        MMJob j1 = {x1, Ws01_l1, a01_l1, YB, t2, t3, CN1 / 16};
        MMJob j2 = {x0, Wt01_l1, a01_l1, YC, t4, t5, CN0 / 16};
        MMJob j3 = {x2, Ws12_l1, a12_l1, YD, t6, t7, CN2 / 16};
        MMJob j4 = {x1, Wt12_l1, a12_l1, YE, t8, t9, CN1 / 16};
        k_l1_fused<<<dim3(5 * mmBlocks + histBlocks), dim3(256), 0, stream>>>(
            j0, j1, j2, j3, j4, P, rp_all + 1, rank_all, mmBlocks);
    }
    // scan + place
    {
        int nb = (TOTSEG + 255) / 256;       // 5860
        int nb2 = (nb + 255) / 256;          // 23
        k_blkscan<<<dim3(nb), dim3(256), 0, stream>>>(rp_all + 1, TOTSEG, bsum);
        k_blkscan<<<dim3(nb2), dim3(256), 0, stream>>>(bsum, nb, bsum2);
        k_scanb<<<dim3(1), dim3(256), 0, stream>>>(bsum2, nb2);
        k_addoff<<<dim3(nb2), dim3(256), 0, stream>>>(bsum, bsum2, nb);
        k_addoff<<<dim3(nb), dim3(256), 0, stream>>>(rp_all + 1, bsum, TOTSEG);
        dim3 gh((Emax + 255) / 256, 7);
        k_place<<<gh, dim3(256), 0, stream>>>(P, rp_all, rank_all, vP_all);
    }

    // ======== LEVEL 1 aggregations ========
    AGG2(bA0, t0, t1, YA, bE1, t5, t2, YB, r0, CN0);   // x_0_to_0 + x_1_to_0
    AGG2(bF1, t3, t4, YC, bE2, t9, t6, YD, r1, CN1);   // x_0_to_1 + x_2_to_1
    AGG1(bF2, t7, t8, YE, r2, CN2);                    // x_1_to_2

    // ======== LEVEL 2: fused per-rank projections, then aggregations ========
    uvec_k<<<dim3(1), dim3(64), 0, stream>>>(Ws01_l2, a01_l2, uuA);
    uvec_k<<<dim3(1), dim3(64), 0, stream>>>(Ws12_l2, a12_l2, uuB);
    {
        int blocks0 = min(1024, (CN0 / 16 + 3) / 4);
        int blocks1 = min(1024, (CN1 / 16 + 3) / 4);
        int blocks2 = min(1024, (CN2 / 16 + 3) / 4);
        // r0: m00 (YA,t0,t1) + tm01 (YC, pt01->t4, q junk->t11)
        mm64_t<1, 0><<<dim3(blocks0), dim3(256), 0, stream>>>(
            r0, W_h0_l2, a_h0_l2, YA, t0, t1,
            Wt01_l2, a01_l2, YC, t4, t11, nullptr, nullptr, CN0 / 16);
        // r1: m11 (YB,t2,t3) + tm12 (YE, pt12->t8, q junk->t11) + vec qs01->t6
        mm64_t<1, 1><<<dim3(blocks1), dim3(256), 0, stream>>>(
            r1, W_h1_l2, a_h1_l2, YB, t2, t3,
            Wt12_l2, a12_l2, YE, t8, t11, uuA + 64, t6, CN1 / 16);
        // r2: m22 (YD,t7,t9) + vec qs12->t10
        mm64_t<0, 1><<<dim3(blocks2), dim3(256), 0, stream>>>(
            r2, W_h2_l2, a_h2_l2, YD, t7, t9,
            nullptr, nullptr, nullptr, nullptr, nullptr, uuB + 64, t10, CN2 / 16);
    }
    AGG1(bA0, t0, t1, YA, r0, CN0);                          // x_0_out
    AGG2(bA1, t2, t3, YB, bF1, t6, t4, YC, r1, CN1);         // x_1_to_1 + x_0_to_1
    AGG2(bC2, t7, t9, YD, bF2, t10, t8, YE, r2, CN2);        // x_2_to_2 + x_1_to_2
}